// Round 8
// baseline (55.444 us; speedup 1.0000x reference)
//
#include <hip/hip_runtime.h>
#include <stdint.h>

// AeTransformer_44839458570443: 3-NN inverse-distance interpolation + (tanh+1)/2.
// xyz1: [B,3,N] fp32, xyz2: [B,3,S] fp32, points2: [B,1,S] fp32 -> out [B,N] fp32.
//
// Selection bit-matches the reference fp32 expanded distance
//   d = (-2*((x*x'+y*y')+z*z') + ||q||^2) + ||p||^2   (fp32, no FMA)
// ordered by (d, index).
// Q=4 register blocking (4 queries/thread): LDS candidate reads amortized 4x.
// PHASE A (proxy, LDS broadcast): 64 groups of 8; FMA distances + min tree;
//   keep 5 best group keys/query (group id in low 6 mantissa bits; lemma: at
//   most 3 groups can have min <= d3; 5 kept for proxy margin).
// PHASE C (global/L1 gathers — off the LDS pipe, no bank conflicts):
//   FMA-proxy rescan of the 40 survivors, 9-bit-quantized 6-slot screen
//   (proven R3), then exact replicated ref_d on 6 + (d,idx) sort + replicated
//   fp32 weight chain (proven R2-R7).
// __launch_bounds__(256,1): we run 1 block/CU by design; allow full VGPR
//   budget so the Q=4 state does NOT spill (R7: VGPR_Count=48 -> scratch).
static constexpr int B = 4;
static constexpr int N = 65536;
static constexpr int S = 512;

__global__ __launch_bounds__(256) void prep_kernel(const float* __restrict__ xyz2,
                                                   float4* __restrict__ ws) {
    int t = blockIdx.x * 256 + threadIdx.x;
    if (t >= B * S) return;
    int b = t >> 9, s = t & 511;
    const float* p = xyz2 + (size_t)b * 3 * S;
    float x = p[s], y = p[s + S], z = p[s + 2 * S];
    float c = __fadd_rn(__fadd_rn(__fmul_rn(x, x), __fmul_rn(y, y)), __fmul_rn(z, z));
    ws[t] = make_float4(x, y, z, c);
}

// Reference-replicated fp32 distance (numpy order, no contraction)
__device__ __forceinline__ float ref_d(float x1, float y1, float z1, float ssrc, float4 p) {
    float dot = __fadd_rn(__fadd_rn(__fmul_rn(x1, p.x), __fmul_rn(y1, p.y)),
                          __fmul_rn(z1, p.z));
    float t = __fmul_rn(dot, -2.0f);
    return __fadd_rn(__fadd_rn(t, ssrc), p.w);
}

#define CAS(da_, ia_, db_, ib_)                                     \
    {                                                               \
        bool sw_ = (db_ < da_) || ((db_ == da_) && (ib_ < ia_));    \
        float tda_ = sw_ ? db_ : da_;                               \
        int tia_ = sw_ ? ib_ : ia_;                                 \
        db_ = sw_ ? da_ : db_;                                      \
        ib_ = sw_ ? ia_ : ib_;                                      \
        da_ = tda_;                                                 \
        ia_ = tia_;                                                 \
    }

#define INS5(a0, a1, a2, a3, a4, k)                                 \
    {                                                               \
        float t4 = __builtin_amdgcn_fmed3f(a3, (k), a4);            \
        float t3 = __builtin_amdgcn_fmed3f(a2, (k), a3);            \
        float t2 = __builtin_amdgcn_fmed3f(a1, (k), a2);            \
        float t1 = __builtin_amdgcn_fmed3f(a0, (k), a1);            \
        a0 = fminf(a0, (k));                                        \
        a1 = t1; a2 = t2; a3 = t3; a4 = t4;                         \
    }

#define INS6(k)                                                     \
    {                                                               \
        float t5 = __builtin_amdgcn_fmed3f(m4, (k), m5);            \
        float t4 = __builtin_amdgcn_fmed3f(m3, (k), m4);            \
        float t3 = __builtin_amdgcn_fmed3f(m2, (k), m3);            \
        float t2 = __builtin_amdgcn_fmed3f(m1, (k), m2);            \
        float t1 = __builtin_amdgcn_fmed3f(m0, (k), m1);            \
        m0 = fminf(m0, (k));                                        \
        m1 = t1; m2 = t2; m3 = t3; m4 = t4; m5 = t5;                \
    }

// Phase-A group processing: 8 candidates (in buf[]), group id gid, 4 queries
#define PROC_GROUP(buf, gid)                                                  \
    {                                                                         \
        _Pragma("unroll") for (int qi = 0; qi < 4; ++qi) {                    \
            float e[8];                                                       \
            _Pragma("unroll") for (int j = 0; j < 8; ++j)                     \
                e[j] = fmaf(nx2[qi], buf[j].x,                                \
                            fmaf(ny2[qi], buf[j].y,                           \
                                 fmaf(nz2[qi], buf[j].z, buf[j].w)));         \
            float mA = fminf(fminf(e[0], e[1]), e[2]);                        \
            float mB = fminf(fminf(e[3], e[4]), e[5]);                        \
            float mC = fminf(fminf(mA, mB), e[6]);                            \
            float gm = fminf(mC, e[7]);                                       \
            float gkey = __uint_as_float(                                     \
                (__float_as_uint(gm + c[qi]) & 0xFFFFFFC0u) | (uint32_t)(gid)); \
            INS5(gk[qi][0], gk[qi][1], gk[qi][2], gk[qi][3], gk[qi][4], gkey); \
        }                                                                     \
    }

__global__ __launch_bounds__(256, 1) void knn3_kernel(const float* __restrict__ xyz1,
                                                      const float* __restrict__ points2,
                                                      const float4* __restrict__ ws,
                                                      float* __restrict__ out) {
    __shared__ float4 tile[S];  // 8 KB candidate table (phase A broadcast only)
    const int tid = threadIdx.x;
    const int b = blockIdx.x >> 6;                 // 64 blocks per batch
    const int n0 = ((blockIdx.x & 63) << 10) + (tid << 2);  // 4 queries/thread

    const float4* __restrict__ wsrc = ws + b * S;
    tile[tid] = wsrc[tid];
    tile[tid + 256] = wsrc[tid + 256];
    __syncthreads();

    // Load 4 consecutive queries per thread (float4-vectorized)
    const float* q = xyz1 + (size_t)b * 3 * N;
    float4 xq = *(const float4*)(q + n0);
    float4 yq = *(const float4*)(q + N + n0);
    float4 zq = *(const float4*)(q + 2 * N + n0);
    float x1[4] = {xq.x, xq.y, xq.z, xq.w};
    float y1[4] = {yq.x, yq.y, yq.z, yq.w};
    float z1[4] = {zq.x, zq.y, zq.z, zq.w};
    float ssrc[4], c[4], nx2[4], ny2[4], nz2[4];
#pragma unroll
    for (int qi = 0; qi < 4; ++qi) {
        ssrc[qi] = __fadd_rn(__fadd_rn(__fmul_rn(x1[qi], x1[qi]), __fmul_rn(y1[qi], y1[qi])),
                             __fmul_rn(z1[qi], z1[qi]));
        c[qi] = ssrc[qi] + 0.25f;  // screen-only bias keeps packed keys > 0
        nx2[qi] = -2.0f * x1[qi];
        ny2[qi] = -2.0f * y1[qi];
        nz2[qi] = -2.0f * z1[qi];
    }

    // ---- Phase A: double-buffered group scan (pA/pB), 5 best groups/query ----
    float gk[4][5];
#pragma unroll
    for (int qi = 0; qi < 4; ++qi)
#pragma unroll
        for (int j = 0; j < 5; ++j) gk[qi][j] = 3.0e38f;

    float4 pA[8], pB[8];
#pragma unroll
    for (int j = 0; j < 8; ++j) pA[j] = tile[j];
    for (int g = 0; g < 64; g += 2) {
#pragma unroll
        for (int j = 0; j < 8; ++j) pB[j] = tile[(g + 1) * 8 + j];
        PROC_GROUP(pA, g);
        if (g + 2 < 64) {
#pragma unroll
            for (int j = 0; j < 8; ++j) pA[j] = tile[(g + 2) * 8 + j];
        }
        PROC_GROUP(pB, g + 1);
    }

    // ---- Phase C: global/L1 gathers; proxy 6-slot screen; exact top-3 ----
    float res[4];
    const float* f = points2 + (size_t)b * S;  // D = 1
#pragma unroll
    for (int qi = 0; qi < 4; ++qi) {
        float m0 = 3.0e38f, m1 = 3.0e38f, m2 = 3.0e38f,
              m3 = 3.0e38f, m4 = 3.0e38f, m5 = 3.0e38f;
#pragma unroll
        for (int t = 0; t < 5; ++t) {
            int gbase = (int)(__float_as_uint(gk[qi][t]) & 63u) << 3;
#pragma unroll
            for (int j = 0; j < 8; ++j) {
                float4 p = wsrc[gbase + j];  // divergent gather, L1-resident
                // cheap FMA proxy (screen only; exact rescore below)
                float e2 = fmaf(nx2[qi], p.x,
                                fmaf(ny2[qi], p.y,
                                     fmaf(nz2[qi], p.z, p.w + c[qi])));
                float k = __uint_as_float((__float_as_uint(e2) & 0xFFFFFE00u) |
                                          (uint32_t)(gbase + j));
                INS6(k);
            }
        }

        int gi[6];
        float dd[6];
        gi[0] = (int)(__float_as_uint(m0) & 511u);
        gi[1] = (int)(__float_as_uint(m1) & 511u);
        gi[2] = (int)(__float_as_uint(m2) & 511u);
        gi[3] = (int)(__float_as_uint(m3) & 511u);
        gi[4] = (int)(__float_as_uint(m4) & 511u);
        gi[5] = (int)(__float_as_uint(m5) & 511u);
#pragma unroll
        for (int j = 0; j < 6; ++j)
            dd[j] = ref_d(x1[qi], y1[qi], z1[qi], ssrc[qi], wsrc[gi[j]]);

#pragma unroll
        for (int pp = 0; pp < 3; ++pp)
#pragma unroll
            for (int i = 4; i >= pp; --i) CAS(dd[i], gi[i], dd[i + 1], gi[i + 1]);

        // Replicate reference weight/interp chain in fp32, nearest-first order
        const float EPS32 = 1e-8f;
        float r0 = __fdiv_rn(1.0f, __fadd_rn(dd[0], EPS32));
        float r1 = __fdiv_rn(1.0f, __fadd_rn(dd[1], EPS32));
        float r2 = __fdiv_rn(1.0f, __fadd_rn(dd[2], EPS32));
        float rs = __fadd_rn(__fadd_rn(r0, r1), r2);
        float w0 = __fdiv_rn(r0, rs);
        float w1 = __fdiv_rn(r1, rs);
        float w2 = __fdiv_rn(r2, rs);
        float interp = __fadd_rn(__fadd_rn(__fmul_rn(f[gi[0]], w0), __fmul_rn(f[gi[1]], w1)),
                                 __fmul_rn(f[gi[2]], w2));
        float t = tanhf(interp);
        res[qi] = __fmul_rn(__fadd_rn(t, 1.0f), 0.5f);
    }

    *(float4*)(out + ((size_t)b << 16) + n0) = make_float4(res[0], res[1], res[2], res[3]);
}

extern "C" void kernel_launch(void* const* d_in, const int* in_sizes, int n_in,
                              void* d_out, int out_size, void* d_ws, size_t ws_size,
                              hipStream_t stream) {
    const float* xyz1 = (const float*)d_in[0];
    const float* xyz2 = (const float*)d_in[1];
    const float* points2 = (const float*)d_in[2];
    float* out = (float*)d_out;
    float4* ws = (float4*)d_ws;  // B*S*16 = 32 KB

    prep_kernel<<<(B * S + 255) / 256, 256, 0, stream>>>(xyz2, ws);
    // 256 blocks x 256 threads, 4 queries/thread (1 block/CU)
    knn3_kernel<<<(B * N) / 1024, 256, 0, stream>>>(xyz1, points2, ws, out);
}

// Round 9
// 42.804 us; speedup vs baseline: 1.2953x; 1.2953x over previous
//
#include <hip/hip_runtime.h>
#include <stdint.h>

// AeTransformer_44839458570443: 3-NN inverse-distance interpolation + (tanh+1)/2.
// xyz1: [B,3,N] fp32, xyz2: [B,3,S] fp32, points2: [B,1,S] fp32 -> out [B,N] fp32.
//
// Selection bit-matches the reference fp32 expanded distance
//   d = (-2*((x*x'+y*y')+z*z') + ||q||^2) + ||p||^2   (fp32, no FMA)
// ordered by (d, index).
// Structure (round 9): Q=4 register blocking + 2-way CANDIDATE SPLIT:
//   each wave pair shares 256 queries (4/lane); wave h of the pair scans
//   candidate half h (32 groups of 8) -> 2048 waves = 2 waves/SIMD (TLP)
//   at the same LDS traffic as Q=4 (2048 broadcast reads/CU).
// PHASE A (proxy, LDS broadcast): per group FMA distances + min tree; keep 5
//   best (group-min | global gid) keys per query (lemma: at most 3 groups can
//   have min <= d3; 5 kept for proxy margin).
// MERGE: 5-key lists exchanged through LDS within the wave pair; partner keys
//   INS5-merged -> global top-5 groups per query.
// PHASE C (global/L1 gathers, off the LDS pipe; R8: zero bank conflicts):
//   waves split the 4 queries 2/2; FMA-proxy rescan of 40 survivors with
//   9-bit-quantized 6-slot screen (proven R3), exact replicated ref_d on 6,
//   (d,idx) sort, replicated fp32 weight chain (proven R2-R8).
static constexpr int B = 4;
static constexpr int N = 65536;
static constexpr int S = 512;

__global__ __launch_bounds__(256) void prep_kernel(const float* __restrict__ xyz2,
                                                   float4* __restrict__ ws) {
    int t = blockIdx.x * 256 + threadIdx.x;
    if (t >= B * S) return;
    int b = t >> 9, s = t & 511;
    const float* p = xyz2 + (size_t)b * 3 * S;
    float x = p[s], y = p[s + S], z = p[s + 2 * S];
    float c = __fadd_rn(__fadd_rn(__fmul_rn(x, x), __fmul_rn(y, y)), __fmul_rn(z, z));
    ws[t] = make_float4(x, y, z, c);
}

// Reference-replicated fp32 distance (numpy order, no contraction)
__device__ __forceinline__ float ref_d(float x1, float y1, float z1, float ssrc, float4 p) {
    float dot = __fadd_rn(__fadd_rn(__fmul_rn(x1, p.x), __fmul_rn(y1, p.y)),
                          __fmul_rn(z1, p.z));
    float t = __fmul_rn(dot, -2.0f);
    return __fadd_rn(__fadd_rn(t, ssrc), p.w);
}

#define CAS(da_, ia_, db_, ib_)                                     \
    {                                                               \
        bool sw_ = (db_ < da_) || ((db_ == da_) && (ib_ < ia_));    \
        float tda_ = sw_ ? db_ : da_;                               \
        int tia_ = sw_ ? ib_ : ia_;                                 \
        db_ = sw_ ? da_ : db_;                                      \
        ib_ = sw_ ? ia_ : ib_;                                      \
        da_ = tda_;                                                 \
        ia_ = tia_;                                                 \
    }

#define INS5(a0, a1, a2, a3, a4, k)                                 \
    {                                                               \
        float t4 = __builtin_amdgcn_fmed3f(a3, (k), a4);            \
        float t3 = __builtin_amdgcn_fmed3f(a2, (k), a3);            \
        float t2 = __builtin_amdgcn_fmed3f(a1, (k), a2);            \
        float t1 = __builtin_amdgcn_fmed3f(a0, (k), a1);            \
        a0 = fminf(a0, (k));                                        \
        a1 = t1; a2 = t2; a3 = t3; a4 = t4;                         \
    }

#define INS6(k)                                                     \
    {                                                               \
        float t5 = __builtin_amdgcn_fmed3f(m4, (k), m5);            \
        float t4 = __builtin_amdgcn_fmed3f(m3, (k), m4);            \
        float t3 = __builtin_amdgcn_fmed3f(m2, (k), m3);            \
        float t2 = __builtin_amdgcn_fmed3f(m1, (k), m2);            \
        float t1 = __builtin_amdgcn_fmed3f(m0, (k), m1);            \
        m0 = fminf(m0, (k));                                        \
        m1 = t1; m2 = t2; m3 = t3; m4 = t4; m5 = t5;                \
    }

// Merge partner's sorted 5-list (query QI) from LDS into own gk[QI]
#define MERGE_Q(QI)                                                           \
    {                                                                         \
        _Pragma("unroll") for (int j = 0; j < 5; ++j) {                       \
            float pk = keys_sh[(QI * 5 + j) * 256 + (tid ^ 64)];              \
            INS5(gk[QI][0], gk[QI][1], gk[QI][2], gk[QI][3], gk[QI][4], pk);  \
        }                                                                     \
    }

// Phase C for query QI (compile-time constant -> all indexing static)
#define PHASE_C(QI, RES)                                                      \
    {                                                                         \
        float m0 = 3.0e38f, m1 = 3.0e38f, m2 = 3.0e38f,                       \
              m3 = 3.0e38f, m4 = 3.0e38f, m5 = 3.0e38f;                       \
        _Pragma("unroll") for (int t = 0; t < 5; ++t) {                       \
            int gbase = (int)(__float_as_uint(gk[QI][t]) & 63u) << 3;         \
            _Pragma("unroll") for (int j = 0; j < 8; ++j) {                   \
                float4 p = wsrc[gbase + j]; /* divergent gather, L1 */        \
                float e2 = fmaf(nx2[QI], p.x,                                 \
                                fmaf(ny2[QI], p.y,                            \
                                     fmaf(nz2[QI], p.z, p.w + c[QI])));       \
                float k = __uint_as_float((__float_as_uint(e2) & 0xFFFFFE00u) \
                                          | (uint32_t)(gbase + j));           \
                INS6(k);                                                      \
            }                                                                 \
        }                                                                     \
        int gi[6];                                                            \
        float dd[6];                                                          \
        gi[0] = (int)(__float_as_uint(m0) & 511u);                            \
        gi[1] = (int)(__float_as_uint(m1) & 511u);                            \
        gi[2] = (int)(__float_as_uint(m2) & 511u);                            \
        gi[3] = (int)(__float_as_uint(m3) & 511u);                            \
        gi[4] = (int)(__float_as_uint(m4) & 511u);                            \
        gi[5] = (int)(__float_as_uint(m5) & 511u);                            \
        _Pragma("unroll") for (int j = 0; j < 6; ++j)                         \
            dd[j] = ref_d(x1[QI], y1[QI], z1[QI], ssrc[QI], wsrc[gi[j]]);     \
        _Pragma("unroll") for (int pp = 0; pp < 3; ++pp)                      \
            _Pragma("unroll") for (int i = 4; i >= pp; --i)                   \
                CAS(dd[i], gi[i], dd[i + 1], gi[i + 1]);                      \
        const float EPS32 = 1e-8f;                                            \
        float r0 = __fdiv_rn(1.0f, __fadd_rn(dd[0], EPS32));                  \
        float r1 = __fdiv_rn(1.0f, __fadd_rn(dd[1], EPS32));                  \
        float r2 = __fdiv_rn(1.0f, __fadd_rn(dd[2], EPS32));                  \
        float rs = __fadd_rn(__fadd_rn(r0, r1), r2);                          \
        float w0 = __fdiv_rn(r0, rs);                                         \
        float w1 = __fdiv_rn(r1, rs);                                         \
        float w2 = __fdiv_rn(r2, rs);                                         \
        float interp = __fadd_rn(__fadd_rn(__fmul_rn(f[gi[0]], w0),           \
                                           __fmul_rn(f[gi[1]], w1)),          \
                                 __fmul_rn(f[gi[2]], w2));                    \
        float th = tanhf(interp);                                             \
        RES = __fmul_rn(__fadd_rn(th, 1.0f), 0.5f);                           \
    }

__global__ __launch_bounds__(256, 2) void knn3_kernel(const float* __restrict__ xyz1,
                                                      const float* __restrict__ points2,
                                                      const float4* __restrict__ ws,
                                                      float* __restrict__ out) {
    __shared__ float4 tile[S];            // 8 KB candidate table (phase A)
    __shared__ float keys_sh[20 * 256];   // 20 KB survivor-key exchange
    const int tid = threadIdx.x;
    const int lane = tid & 63;
    const int wid = tid >> 6;
    const int h = wid & 1;                // candidate half this wave scans
    const int pr = wid >> 1;              // wave-pair id (query group)

    const int b = blockIdx.x >> 7;        // 128 blocks per batch
    const int n0 = ((blockIdx.x & 127) << 9) + ((pr << 6) + lane) * 4;

    const float4* __restrict__ wsrc = ws + b * S;
    tile[tid] = wsrc[tid];
    tile[tid + 256] = wsrc[tid + 256];
    __syncthreads();

    // 4 consecutive queries per thread (float4-vectorized loads)
    const float* q = xyz1 + (size_t)b * 3 * N;
    float4 xq = *(const float4*)(q + n0);
    float4 yq = *(const float4*)(q + N + n0);
    float4 zq = *(const float4*)(q + 2 * N + n0);
    float x1[4] = {xq.x, xq.y, xq.z, xq.w};
    float y1[4] = {yq.x, yq.y, yq.z, yq.w};
    float z1[4] = {zq.x, zq.y, zq.z, zq.w};
    float ssrc[4], c[4], nx2[4], ny2[4], nz2[4];
#pragma unroll
    for (int qi = 0; qi < 4; ++qi) {
        ssrc[qi] = __fadd_rn(__fadd_rn(__fmul_rn(x1[qi], x1[qi]), __fmul_rn(y1[qi], y1[qi])),
                             __fmul_rn(z1[qi], z1[qi]));
        c[qi] = ssrc[qi] + 0.25f;  // screen-only bias keeps packed keys > 0
        nx2[qi] = -2.0f * x1[qi];
        ny2[qi] = -2.0f * y1[qi];
        nz2[qi] = -2.0f * z1[qi];
    }

    // ---- Phase A: scan own 32 groups; keep 5 best (min | global gid)/query ----
    float gk[4][5];
#pragma unroll
    for (int qi = 0; qi < 4; ++qi)
#pragma unroll
        for (int j = 0; j < 5; ++j) gk[qi][j] = 3.0e38f;

    const int gid0 = h << 5;  // global group id base for this half
#pragma unroll 2
    for (int g = 0; g < 32; ++g) {
        const int gid = gid0 + g;
        float4 p[8];
#pragma unroll
        for (int j = 0; j < 8; ++j) p[j] = tile[gid * 8 + j];  // broadcast
#pragma unroll
        for (int qi = 0; qi < 4; ++qi) {
            float e[8];
#pragma unroll
            for (int j = 0; j < 8; ++j)
                e[j] = fmaf(nx2[qi], p[j].x,
                            fmaf(ny2[qi], p[j].y, fmaf(nz2[qi], p[j].z, p[j].w)));
            float mA = fminf(fminf(e[0], e[1]), e[2]);
            float mB = fminf(fminf(e[3], e[4]), e[5]);
            float mC = fminf(fminf(mA, mB), e[6]);
            float gm = fminf(mC, e[7]);
            float gkey = __uint_as_float((__float_as_uint(gm + c[qi]) & 0xFFFFFFC0u) |
                                         (uint32_t)gid);
            INS5(gk[qi][0], gk[qi][1], gk[qi][2], gk[qi][3], gk[qi][4], gkey);
        }
    }

    // publish all 20 keys ([slot][tid] layout -> stride-1, conflict-free)
#pragma unroll
    for (int qi = 0; qi < 4; ++qi)
#pragma unroll
        for (int j = 0; j < 5; ++j)
            keys_sh[(qi * 5 + j) * 256 + tid] = gk[qi][j];
    __syncthreads();

    // ---- Merge partner halves + Phase C (2 queries per wave) ----
    const float* f = points2 + (size_t)b * S;  // D = 1
    if (h == 0) {
        MERGE_Q(0); MERGE_Q(1);
        float resA, resB;
        PHASE_C(0, resA);
        PHASE_C(1, resB);
        *(float2*)(out + ((size_t)b << 16) + n0) = make_float2(resA, resB);
    } else {
        MERGE_Q(2); MERGE_Q(3);
        float resA, resB;
        PHASE_C(2, resA);
        PHASE_C(3, resB);
        *(float2*)(out + ((size_t)b << 16) + n0 + 2) = make_float2(resA, resB);
    }
}

extern "C" void kernel_launch(void* const* d_in, const int* in_sizes, int n_in,
                              void* d_out, int out_size, void* d_ws, size_t ws_size,
                              hipStream_t stream) {
    const float* xyz1 = (const float*)d_in[0];
    const float* xyz2 = (const float*)d_in[1];
    const float* points2 = (const float*)d_in[2];
    float* out = (float*)d_out;
    float4* ws = (float4*)d_ws;  // B*S*16 = 32 KB

    prep_kernel<<<(B * S + 255) / 256, 256, 0, stream>>>(xyz2, ws);
    // 512 blocks x 256 threads: wave pairs share 256 queries, split candidates
    knn3_kernel<<<(B * N) / 512, 256, 0, stream>>>(xyz1, points2, ws, out);
}